// Round 4
// baseline (648.994 us; speedup 1.0000x reference)
//
#include <hip/hip_runtime.h>
#include <hip/hip_bf16.h>

// Problem constants
#define NNEUR 8192
#define NCONV 64
#define LYC   36
#define LXC   36
#define BATCH 256
#define KRAW  1296   // 36*36
#define KPAD  1344   // 21*64
#define KITER 21     // KPAD/64
#define MROWS 16384  // BATCH*NCONV
#define BM 256
#define BN 128
#define BK 64
// Staged-chunk geometry: one chunk = 16 B = 8 halfs.
#define ACH_PER_IT 2048   // BM*BK/8
#define BCH_PER_IT 1024   // BN*BK/8
#define A_TILE_H   (KITER * ACH_PER_IT * 8)  // halfs per m-tile = 344064
#define B_TILE_H   (KITER * BCH_PER_IT * 8)  // halfs per n-tile = 172032

typedef __attribute__((ext_vector_type(8))) _Float16 half8;
typedef __attribute__((ext_vector_type(4))) float f32x4;
typedef __attribute__((ext_vector_type(16))) float f32x16;

__device__ __forceinline__ void async_copy16(const void* g, void* l) {
  __builtin_amdgcn_global_load_lds(
      (const __attribute__((address_space(1))) void*)g,
      (__attribute__((address_space(3))) void*)l, 16, 0, 0);
}

// Prep v2: identical output images to the round-0 prep (verified), but one
// thread produces one complete 64-half row-chunk instead of one 16B slot.
// Image layout per (tile, it): half offset r*64 + s*8 holds source chunk
// c = (s - r)&7 of row r (chunk = 16B of the row's BK=64 k-slice).
// Per thread: read 256B contiguous (fully-used cache lines), rotate the 8
// chunks in registers, write 128B contiguous. Wave: 32KB sequential store.
// grid (KITER, 64), 256 threads: A: it = bx, mtile = by, r = t (256 rows);
// B (threads t<128 additionally): it = bx, ntile = by, r = t (128 rows).
__global__ __launch_bounds__(256) void prep_kernel(
    const float* __restrict__ conv, const float* __restrict__ Wy,
    const float* __restrict__ Wx, _Float16* __restrict__ A,
    _Float16* __restrict__ B) {
  const int t = threadIdx.x;
  const int it = blockIdx.x;
  const int tile = blockIdx.y;
  const int k0 = it * 64;

  // ---- A part: conv -> f16, swizzled image ----
  {
    const int r = t;
    const int grow = tile * BM + r;
    const float* src = conv + (size_t)grow * KRAW + k0;
    half8 h[8];
    if (k0 + 64 <= KRAW) {  // full 8 chunks valid (it < 20)
#pragma unroll
      for (int c = 0; c < 8; c++)
#pragma unroll
        for (int e = 0; e < 8; e++) h[c][e] = (_Float16)src[c * 8 + e];
    } else {  // it == 20 tail: only chunks with k0+c*8+8 <= KRAW valid
#pragma unroll
      for (int c = 0; c < 8; c++) {
        if (k0 + c * 8 + 8 <= KRAW) {
#pragma unroll
          for (int e = 0; e < 8; e++) h[c][e] = (_Float16)src[c * 8 + e];
        } else {
#pragma unroll
          for (int e = 0; e < 8; e++) h[c][e] = (_Float16)0.f;
        }
      }
    }
    half8* dst = (half8*)(A + (size_t)tile * A_TILE_H +
                          (size_t)it * (ACH_PER_IT * 8) + (size_t)r * 64);
#pragma unroll
    for (int s = 0; s < 8; s++) dst[s] = h[(s - r) & 7];
  }

  // ---- B part: Wy*Wx*256 -> f16, swizzled image (128 rows) ----
  if (t < 128) {
    const int r = t;
    const int n = tile * BN + r;
    const float* wyn = Wy + n * LYC;
    const float* wxn = Wx + n * LXC;
    int y = k0 / LXC;
    int x = k0 - y * LXC;
    float wy = wyn[y];  // k0 <= 1280 < KRAW -> y <= 35, safe
    half8 h[8];
#pragma unroll
    for (int j = 0; j < 64; j++) {
      float v = 0.f;
      if (k0 + j < KRAW) v = wy * wxn[x] * 256.f;
      h[j >> 3][j & 7] = (_Float16)v;
      if (++x == LXC) {
        x = 0;
        ++y;
        wy = (k0 + j + 1 < KRAW) ? wyn[y] : 0.f;
      }
    }
    half8* dst = (half8*)(B + (size_t)tile * B_TILE_H +
                          (size_t)it * (BCH_PER_IT * 8) + (size_t)r * 64);
#pragma unroll
    for (int s = 0; s < 8; s++) dst[s] = h[(s - r) & 7];
  }
}

// Fused GEMM: block tile 256(M)x128(N), BK=64, 4 waves each 128x64 using
// 32x32x16 f16 MFMA (acc 8 x f32x16 = 128 AGPR). Epilogue contracts the 64
// channels with Wc, adds bias, ELU. LDS 48 KB single-buffered.
// (Byte-identical to the round-0 kernel measured at 357 us / MfmaUtil 48%:
// the 2-barrier single-buffer schedule with ~2.5 blocks/CU inter-block
// overlap empirically beats 512-thread counted-vmcnt and per-phase-barrier
// variants on this 21-K-tile problem -- see rounds 1-3 post-mortems.)
__global__ __launch_bounds__(256, 3) void gemm_fused_kernel(
    const _Float16* __restrict__ A, const _Float16* __restrict__ B,
    const float* __restrict__ Wc, const float* __restrict__ bias,
    float* __restrict__ out) {
  __shared__ _Float16 As[BM * BK];  // 32 KB
  __shared__ _Float16 Bs[BN * BK];  // 16 KB

  // XCD swizzle: xcd = bid&7; within an XCD, n varies fastest so the 8
  // blocks sharing one A-tile are consecutive; B panel (8 n-tiles, 2.75 MB)
  // stays L2-resident per XCD.
  const int bid = blockIdx.x;      // 0..4095
  const int l = bid >> 3;          // 0..511
  const int ntile = (bid & 7) * 8 + (l & 7);  // 0..63
  const int mtile = l >> 3;                   // 0..63
  const int tileN = ntile * BN;

  const int t = threadIdx.x;
  const int lane = t & 63;
  const int wave = t >> 6;
  const int wm = wave >> 1, wn = wave & 1;  // 2x2 waves; wave tile 128x64
  const int r32 = lane & 31, hh = lane >> 5;

  f32x16 acc[4][2] = {};  // [mb][nb], mb: 4x32 rows, nb: 2x32 cols

  const _Float16* pA = A + (size_t)mtile * A_TILE_H;
  const _Float16* pB = B + (size_t)ntile * B_TILE_H;
  _Float16* lA = As + t * 8;
  _Float16* lB = Bs + t * 8;

  for (int it = 0; it < KITER; it++) {
    const _Float16* sA = pA + (size_t)it * (ACH_PER_IT * 8) + t * 8;
    const _Float16* sB = pB + (size_t)it * (BCH_PER_IT * 8) + t * 8;
#pragma unroll
    for (int i = 0; i < 8; i++) async_copy16(sA + i * 2048, lA + i * 2048);
#pragma unroll
    for (int i = 0; i < 4; i++) async_copy16(sB + i * 2048, lB + i * 2048);
    __syncthreads();

#pragma unroll
    for (int ks = 0; ks < 4; ks++) {
      const int cc = 2 * ks + hh;  // source chunk for this k-substep
      half8 bf[2];
#pragma unroll
      for (int nb = 0; nb < 2; nb++) {
        const int r = wn * 64 + nb * 32 + r32;
        bf[nb] = *(const half8*)(Bs + r * 64 + ((cc + r) & 7) * 8);
      }
#pragma unroll
      for (int mb = 0; mb < 4; mb++) {
        const int r = wm * 128 + mb * 32 + r32;
        const half8 af = *(const half8*)(As + r * 64 + ((cc + r) & 7) * 8);
#pragma unroll
        for (int nb = 0; nb < 2; nb++)
          acc[mb][nb] = __builtin_amdgcn_mfma_f32_32x32x16_f16(
              af, bf[nb], acc[mb][nb], 0, 0, 0);
      }
    }
    __syncthreads();
  }

  // Epilogue. C/D layout (32x32): col = lane&31, row = (reg&3)+8*(reg>>2)+4*hh.
  // Wave rows = 128 = 2 images x 64 channels; mb pairs (0,1)->img0, (2,3)->img1;
  // channel = (mb&1)*32 + row.
  const int ibase = mtile * 4 + wm * 2;
  float v[2][2];  // [img][nb]
#pragma unroll
  for (int nb = 0; nb < 2; nb++) {
    const int n_g = tileN + wn * 64 + nb * 32 + r32;
    const float* wc = Wc + (size_t)n_g * NCONV;
    f32x4 w[2][4];
#pragma unroll
    for (int hf = 0; hf < 2; hf++)
#pragma unroll
      for (int g = 0; g < 4; g++)
        w[hf][g] = *(const f32x4*)(wc + hf * 32 + hh * 4 + g * 8);
#pragma unroll
    for (int img = 0; img < 2; img++) {
      float p = 0.f;
#pragma unroll
      for (int hf = 0; hf < 2; hf++)
#pragma unroll
        for (int g = 0; g < 4; g++)
#pragma unroll
          for (int q = 0; q < 4; q++)
            p += acc[img * 2 + hf][nb][g * 4 + q] * w[hf][g][q];
      p += __shfl_xor(p, 32);
      v[img][nb] = p;
    }
  }
  // Each lane writes image hh (its half), both nb; values identical per half.
  const int img = ibase + hh;
#pragma unroll
  for (int nb = 0; nb < 2; nb++) {
    const int n_out = tileN + wn * 64 + nb * 32 + r32;
    float z = v[hh][nb] * 0.00390625f + bias[n_out];  // undo x256 scaling
    z = z > 0.f ? z : (__expf(z) - 1.f);
    out[(size_t)img * NNEUR + n_out] = z;
  }
}

extern "C" void kernel_launch(void* const* d_in, const int* in_sizes, int n_in,
                              void* d_out, int out_size, void* d_ws,
                              size_t ws_size, hipStream_t stream) {
  const float* conv = (const float*)d_in[0];
  const float* Wc = (const float*)d_in[1];
  const float* Wy = (const float*)d_in[2];
  const float* Wx = (const float*)d_in[3];
  const float* bias = (const float*)d_in[4];
  float* out = (float*)d_out;

  _Float16* Abuf = (_Float16*)d_ws;                                      // 44.0 MB
  _Float16* Bbuf = (_Float16*)((char*)d_ws + (size_t)MROWS * KPAD * 2);  // 22.0 MB

  prep_kernel<<<dim3(KITER, 64), 256, 0, stream>>>(conv, Wy, Wx, Abuf, Bbuf);
  gemm_fused_kernel<<<4096, 256, 0, stream>>>(Abuf, Bbuf, Wc, bias, out);
}

// Round 5
// 485.569 us; speedup vs baseline: 1.3366x; 1.3366x over previous
//
#include <hip/hip_runtime.h>
#include <hip/hip_bf16.h>

// Problem constants
#define NNEUR 8192
#define NCONV 64
#define LYC   36
#define LXC   36
#define BATCH 256
#define KRAW  1296   // 36*36
#define KPAD  1344   // 21*64
#define KITER 21     // KPAD/64
#define MROWS 16384  // BATCH*NCONV
#define BM 256
#define BN 128
#define BK 64
// Staged-chunk geometry: one chunk = 16 B = 8 halfs.
#define ACH_PER_IT 2048   // BM*BK/8
#define BCH_PER_IT 1024   // BN*BK/8
#define A_TILE_H   (KITER * ACH_PER_IT * 8)  // halfs per m-tile = 344064
#define B_TILE_H   (KITER * BCH_PER_IT * 8)  // halfs per n-tile = 172032

typedef __attribute__((ext_vector_type(8))) _Float16 half8;
typedef __attribute__((ext_vector_type(4))) float f32x4;
typedef __attribute__((ext_vector_type(16))) float f32x16;

__device__ __forceinline__ void async_copy16(const void* g, void* l) {
  __builtin_amdgcn_global_load_lds(
      (const __attribute__((address_space(1))) void*)g,
      (__attribute__((address_space(3))) void*)l, 16, 0, 0);
}

// Prep v3: CHUNK-MAJOR images. Per (tile, it) the image holds 16B chunks at
// position p: A: p = c*256 + r (c = k-chunk 0..7, r = row 0..255);
//             B: p = c*128 + r.
// The GEMM stages position p to LDS chunk p (linear copy), so LDS ends up
// chunk-major and every MFMA fragment read (fixed chunk, 32 consecutive
// rows) is 512B CONTIGUOUS per half-wave -> zero bank conflicts, no XOR
// address math. Prep thread mapping is round-0's coalesced pattern:
// 8 lanes = 8 chunks of one row (256B contiguous read per lane-octet);
// writes land in 128B-contiguous per-chunk groups.
// grid: x = 0..167 -> A (it = x>>3, i = x&7, mtile = y);
//       x = 168..251 -> B (x'=x-168, it = x'>>2, i4 = x'&3, ntile = y).
__global__ __launch_bounds__(256) void prep_kernel(
    const float* __restrict__ conv, const float* __restrict__ Wy,
    const float* __restrict__ Wx, _Float16* __restrict__ A,
    _Float16* __restrict__ B) {
  const int t = threadIdx.x;
  const int bx = blockIdx.x;
  const int tile = blockIdx.y;
  const int c = t & 7;  // chunk index within the BK=64 row
  half8 h;
  if (bx < 168) {  // A part: conv -> f16
    const int it = bx >> 3, i = bx & 7;
    const int r = (t >> 3) + 32 * i;                 // row in tile, 0..255
    const int k0 = it * 64 + c * 8;
    const int grow = tile * BM + r;
    if (k0 < KRAW) {  // chunk fully valid (KRAW is a multiple of 8)
      const float* s = conv + (size_t)grow * KRAW + k0;
#pragma unroll
      for (int e = 0; e < 8; e++) h[e] = (_Float16)s[e];
    } else {
#pragma unroll
      for (int e = 0; e < 8; e++) h[e] = (_Float16)0.f;
    }
    *(half8*)(A + (size_t)tile * A_TILE_H + (size_t)it * (ACH_PER_IT * 8) +
              ((size_t)c * 256 + r) * 8) = h;
  } else {  // B part: Wy*Wx*256 -> f16
    const int bxp = bx - 168;                        // 0..83
    const int it = bxp >> 2, i4 = bxp & 3;           // it 0..20
    const int r = (t >> 3) + 32 * i4;                // row in tile, 0..127
    const int k0 = it * 64 + c * 8;
    const int n = tile * BN + r;
    if (k0 < KRAW) {  // chunk fully valid
      const float* wyn = Wy + n * LYC;
      const float* wxn = Wx + n * LXC;
      int y = k0 / LXC;
      int x = k0 - y * LXC;
#pragma unroll
      for (int e = 0; e < 8; e++) {
        h[e] = (_Float16)(wyn[y] * wxn[x] * 256.f);
        if (++x == LXC) { x = 0; ++y; }
      }
    } else {
#pragma unroll
      for (int e = 0; e < 8; e++) h[e] = (_Float16)0.f;
    }
    *(half8*)(B + (size_t)tile * B_TILE_H + (size_t)it * (BCH_PER_IT * 8) +
              ((size_t)c * 128 + r) * 8) = h;
  }
}

// Fused GEMM: block tile 256(M)x128(N), BK=64, 4 waves each 128x64 using
// 32x32x16 f16 MFMA (acc 8 x f32x16 = 128 AGPR). Identical schedule to the
// proven 357us round-0 kernel (2-barrier single-buffer, ~2.5 blocks/CU
// inter-block overlap); only the LDS layout changed to chunk-major so
// fragment reads are 512B-contiguous per half-wave (conflict-free).
// Epilogue contracts the 64 channels with Wc, adds bias, ELU. LDS 48 KB.
__global__ __launch_bounds__(256, 3) void gemm_fused_kernel(
    const _Float16* __restrict__ A, const _Float16* __restrict__ B,
    const float* __restrict__ Wc, const float* __restrict__ bias,
    float* __restrict__ out) {
  __shared__ _Float16 As[BM * BK];  // 32 KB, chunk-major: (c,r) at c*2048+r*8
  __shared__ _Float16 Bs[BN * BK];  // 16 KB, chunk-major: (c,r) at c*1024+r*8

  // XCD swizzle: xcd = bid&7; within an XCD, n varies fastest so the 8
  // blocks sharing one A-tile are consecutive; B panel (8 n-tiles, 2.75 MB)
  // stays L2-resident per XCD.
  const int bid = blockIdx.x;      // 0..4095
  const int l = bid >> 3;          // 0..511
  const int ntile = (bid & 7) * 8 + (l & 7);  // 0..63
  const int mtile = l >> 3;                   // 0..63
  const int tileN = ntile * BN;

  const int t = threadIdx.x;
  const int lane = t & 63;
  const int wave = t >> 6;
  const int wm = wave >> 1, wn = wave & 1;  // 2x2 waves; wave tile 128x64
  const int r32 = lane & 31, hh = lane >> 5;

  f32x16 acc[4][2] = {};  // [mb][nb], mb: 4x32 rows, nb: 2x32 cols

  const _Float16* pA = A + (size_t)mtile * A_TILE_H;
  const _Float16* pB = B + (size_t)ntile * B_TILE_H;
  _Float16* lA = As + t * 8;
  _Float16* lB = Bs + t * 8;

  for (int it = 0; it < KITER; it++) {
    const _Float16* sA = pA + (size_t)it * (ACH_PER_IT * 8) + t * 8;
    const _Float16* sB = pB + (size_t)it * (BCH_PER_IT * 8) + t * 8;
#pragma unroll
    for (int i = 0; i < 8; i++) async_copy16(sA + i * 2048, lA + i * 2048);
#pragma unroll
    for (int i = 0; i < 4; i++) async_copy16(sB + i * 2048, lB + i * 2048);
    __syncthreads();

#pragma unroll
    for (int ks = 0; ks < 4; ks++) {
      const int cc = 2 * ks + hh;  // source chunk for this k-substep
      half8 bf[2];
#pragma unroll
      for (int nb = 0; nb < 2; nb++) {
        const int r = wn * 64 + nb * 32 + r32;
        bf[nb] = *(const half8*)(Bs + cc * 1024 + r * 8);
      }
#pragma unroll
      for (int mb = 0; mb < 4; mb++) {
        const int r = wm * 128 + mb * 32 + r32;
        const half8 af = *(const half8*)(As + cc * 2048 + r * 8);
#pragma unroll
        for (int nb = 0; nb < 2; nb++)
          acc[mb][nb] = __builtin_amdgcn_mfma_f32_32x32x16_f16(
              af, bf[nb], acc[mb][nb], 0, 0, 0);
      }
    }
    __syncthreads();
  }

  // Epilogue. C/D layout (32x32): col = lane&31, row = (reg&3)+8*(reg>>2)+4*hh.
  // Wave rows = 128 = 2 images x 64 channels; mb pairs (0,1)->img0, (2,3)->img1;
  // channel = (mb&1)*32 + row.
  const int ibase = mtile * 4 + wm * 2;
  float v[2][2];  // [img][nb]
#pragma unroll
  for (int nb = 0; nb < 2; nb++) {
    const int n_g = tileN + wn * 64 + nb * 32 + r32;
    const float* wc = Wc + (size_t)n_g * NCONV;
    f32x4 w[2][4];
#pragma unroll
    for (int hf = 0; hf < 2; hf++)
#pragma unroll
      for (int g = 0; g < 4; g++)
        w[hf][g] = *(const f32x4*)(wc + hf * 32 + hh * 4 + g * 8);
#pragma unroll
    for (int img = 0; img < 2; img++) {
      float p = 0.f;
#pragma unroll
      for (int hf = 0; hf < 2; hf++)
#pragma unroll
        for (int g = 0; g < 4; g++)
#pragma unroll
          for (int q = 0; q < 4; q++)
            p += acc[img * 2 + hf][nb][g * 4 + q] * w[hf][g][q];
      p += __shfl_xor(p, 32);
      v[img][nb] = p;
    }
  }
  // Each lane writes image hh (its half), both nb; values identical per half.
  const int img = ibase + hh;
#pragma unroll
  for (int nb = 0; nb < 2; nb++) {
    const int n_out = tileN + wn * 64 + nb * 32 + r32;
    float z = v[hh][nb] * 0.00390625f + bias[n_out];  // undo x256 scaling
    z = z > 0.f ? z : (__expf(z) - 1.f);
    out[(size_t)img * NNEUR + n_out] = z;
  }
}

extern "C" void kernel_launch(void* const* d_in, const int* in_sizes, int n_in,
                              void* d_out, int out_size, void* d_ws,
                              size_t ws_size, hipStream_t stream) {
  const float* conv = (const float*)d_in[0];
  const float* Wc = (const float*)d_in[1];
  const float* Wy = (const float*)d_in[2];
  const float* Wx = (const float*)d_in[3];
  const float* bias = (const float*)d_in[4];
  float* out = (float*)d_out;

  _Float16* Abuf = (_Float16*)d_ws;                                      // 44.0 MB
  _Float16* Bbuf = (_Float16*)((char*)d_ws + (size_t)MROWS * KPAD * 2);  // 22.0 MB

  prep_kernel<<<dim3(252, 64), 256, 0, stream>>>(conv, Wy, Wx, Abuf, Bbuf);
  gemm_fused_kernel<<<4096, 256, 0, stream>>>(Abuf, Bbuf, Wc, bias, out);
}